// Round 8
// baseline (179.842 us; speedup 1.0000x reference)
//
#include <hip/hip_runtime.h>
#include <math.h>

#define IN_CH 128
#define OUT_CH 64
#define NEG_SLOPE 0.2f

// ---------- bf16 helpers ----------
__device__ __forceinline__ unsigned short f2bf(float f) {
    unsigned u = __float_as_uint(f);
    unsigned r = (u + 0x7FFFu + ((u >> 16) & 1u)) >> 16;   // round-nearest-even
    return (unsigned short)r;
}

// ---------- edge dtype sniff: int64 little-endian => odd int32 words are 0 ----------
__device__ __forceinline__ bool sniff_is64(const void* edges) {
    const unsigned* up = (const unsigned*)edges;
    bool is64 = true;
#pragma unroll
    for (int k = 0; k < 16; k++) is64 = is64 && (up[2 * k + 1] == 0u);
    return is64;
}

// ---------- K1 (fused, interleaved): even blocks do mm, odd blocks do count ----------
// NO LDS anywhere in this kernel: W reads are wave-broadcast and L1-hot, so the
// mm path streams W straight from global. Zero LDS -> 8 blocks/CU (VGPR-bound),
// giving the latency-bound count path 3x more waves than the 32KB-LDS version.
__global__ __launch_bounds__(256) void k_mm_count(
        const float* __restrict__ x, const float* __restrict__ W,
        const float* __restrict__ att, unsigned short* __restrict__ h16,
        float* __restrict__ asrc, float* __restrict__ adst, int N,
        const void* __restrict__ edges, int* __restrict__ counts,
        unsigned short* __restrict__ rank, int E, int mmb, int cntb) {
    int t = threadIdx.x;
    int bid = blockIdx.x;
    int lo = min(mmb, cntb), M2 = 2 * lo;
    int role, id;   // role 0 = mm, 1 = count
    if (bid < M2) { role = bid & 1; id = bid >> 1; }
    else          { role = (mmb > cntb) ? 0 : 1; id = bid - M2 + lo; }

    if (role == 1) {
        // ----- count path: 4 edges/thread -----
        int e0 = (id * 256 + t) * 4;
        if (e0 >= E) return;
        int d[4];
        if (sniff_is64(edges)) {
            const long long* p = (const long long*)edges;
            if (e0 + 3 < E) {
                int4 v0 = *(const int4*)&p[(size_t)E + e0];       // 16B aligned
                int4 v1 = *(const int4*)&p[(size_t)E + e0 + 2];
                d[0] = v0.x; d[1] = v0.z; d[2] = v1.x; d[3] = v1.z;
            } else {
                for (int i = 0; i < 4; i++)
                    d[i] = (e0 + i < E) ? (int)p[(size_t)E + e0 + i] : 0;
            }
        } else {
            const int* p = (const int*)edges;
            if (e0 + 3 < E) {
                int4 v = *(const int4*)&p[E + e0];
                d[0] = v.x; d[1] = v.y; d[2] = v.z; d[3] = v.w;
            } else {
                for (int i = 0; i < 4; i++)
                    d[i] = (e0 + i < E) ? p[E + e0 + i] : 0;
            }
        }
        if (e0 + 3 < E) {
            ushort4 r;
            r.x = (unsigned short)atomicAdd(counts + d[0], 1);
            r.y = (unsigned short)atomicAdd(counts + d[1], 1);
            r.z = (unsigned short)atomicAdd(counts + d[2], 1);
            r.w = (unsigned short)atomicAdd(counts + d[3], 1);
            *(ushort4*)&rank[e0] = r;
        } else {
            for (int i = 0; i < 4; i++)
                if (e0 + i < E)
                    rank[e0 + i] = (unsigned short)atomicAdd(counts + d[i], 1);
        }
        return;
    }

    // ----- mm path (W direct from global, L1-hot broadcast loads) -----
    int cg = t & 15, g = t >> 4;
    float4 att_d = *(const float4*)&att[cg * 4];        // dst half: att[0:64]
    float4 att_s = *(const float4*)&att[64 + cg * 4];   // src half: att[64:128]

    int n0 = id * 64 + g * 4;
    int nn[4];
#pragma unroll
    for (int m = 0; m < 4; m++) nn[m] = min(n0 + m, N - 1);

    float4 acc[4];
#pragma unroll
    for (int m = 0; m < 4; m++) acc[m] = make_float4(0.f, 0.f, 0.f, 0.f);

#pragma unroll 2
    for (int k4 = 0; k4 < IN_CH / 4; k4++) {
        float4 xv[4];
#pragma unroll
        for (int m = 0; m < 4; m++)
            xv[m] = *(const float4*)&x[(size_t)nn[m] * IN_CH + k4 * 4];
        float4 wv[4];
#pragma unroll
        for (int j = 0; j < 4; j++)
            wv[j] = *(const float4*)&W[(k4 * 4 + j) * OUT_CH + cg * 4];
#pragma unroll
        for (int m = 0; m < 4; m++) {
            acc[m].x = fmaf(xv[m].x, wv[0].x, acc[m].x);
            acc[m].y = fmaf(xv[m].x, wv[0].y, acc[m].y);
            acc[m].z = fmaf(xv[m].x, wv[0].z, acc[m].z);
            acc[m].w = fmaf(xv[m].x, wv[0].w, acc[m].w);
            acc[m].x = fmaf(xv[m].y, wv[1].x, acc[m].x);
            acc[m].y = fmaf(xv[m].y, wv[1].y, acc[m].y);
            acc[m].z = fmaf(xv[m].y, wv[1].z, acc[m].z);
            acc[m].w = fmaf(xv[m].y, wv[1].w, acc[m].w);
            acc[m].x = fmaf(xv[m].z, wv[2].x, acc[m].x);
            acc[m].y = fmaf(xv[m].z, wv[2].y, acc[m].y);
            acc[m].z = fmaf(xv[m].z, wv[2].z, acc[m].z);
            acc[m].w = fmaf(xv[m].z, wv[2].w, acc[m].w);
            acc[m].x = fmaf(xv[m].w, wv[3].x, acc[m].x);
            acc[m].y = fmaf(xv[m].w, wv[3].y, acc[m].y);
            acc[m].z = fmaf(xv[m].w, wv[3].z, acc[m].z);
            acc[m].w = fmaf(xv[m].w, wv[3].w, acc[m].w);
        }
    }

#pragma unroll
    for (int m = 0; m < 4; m++) {
        int node = n0 + m;
        if (node < N) {
            ushort4 hv;
            hv.x = f2bf(acc[m].x);
            hv.y = f2bf(acc[m].y);
            hv.z = f2bf(acc[m].z);
            hv.w = f2bf(acc[m].w);
            *(ushort4*)&h16[(size_t)node * OUT_CH + cg * 4] = hv;
        }
        float pd = acc[m].x * att_d.x + acc[m].y * att_d.y +
                   acc[m].z * att_d.z + acc[m].w * att_d.w;
        float ps = acc[m].x * att_s.x + acc[m].y * att_s.y +
                   acc[m].z * att_s.z + acc[m].w * att_s.w;
#pragma unroll
        for (int msk = 1; msk < 16; msk <<= 1) {
            pd += __shfl_xor(pd, msk, 64);
            ps += __shfl_xor(ps, msk, 64);
        }
        if (cg == 0 && node < N) { adst[node] = pd; asrc[node] = ps; }
    }
}

// ---------- K2a: per-block sums of counts (1024 elems/block) ----------
__global__ __launch_bounds__(256) void k_scanA(const int* __restrict__ counts,
                                               int* __restrict__ partials, int N) {
    __shared__ int red[256];
    int t = threadIdx.x;
    int base = blockIdx.x * 1024 + t * 4;
    int s = 0;
    if (base + 3 < N) {
        int4 v = *(const int4*)(counts + base);
        s = v.x + v.y + v.z + v.w;
    } else {
        for (int i = 0; i < 4; i++) if (base + i < N) s += counts[base + i];
    }
    red[t] = s;
    __syncthreads();
    for (int off = 128; off > 0; off >>= 1) {
        if (t < off) red[t] += red[t + off];
        __syncthreads();
    }
    if (t == 0) partials[blockIdx.x] = red[0];
}

// ---------- K2b: each block scans the partials itself, then re-scans its chunk ----------
__global__ __launch_bounds__(256) void k_scanC(const int* __restrict__ counts,
                                               const int* __restrict__ partials,
                                               int nb, int total,
                                               int* __restrict__ rowptr, int N) {
    __shared__ int shp[256];
    __shared__ int sh[256];
    int t = threadIdx.x;
    shp[t] = (t < nb) ? partials[t] : 0;
    __syncthreads();
    for (int off = 1; off < 256; off <<= 1) {
        int v = (t >= off) ? shp[t - off] : 0;
        __syncthreads();
        shp[t] += v;
        __syncthreads();
    }
    int base_blk = (blockIdx.x == 0) ? 0 : shp[blockIdx.x - 1];

    int base = blockIdx.x * 1024 + t * 4;
    int c[4];
    int s = 0;
#pragma unroll
    for (int i = 0; i < 4; i++) {
        int idx = base + i;
        c[i] = (idx < N) ? counts[idx] : 0;
        s += c[i];
    }
    sh[t] = s;
    __syncthreads();
    for (int off = 1; off < 256; off <<= 1) {
        int v = (t >= off) ? sh[t - off] : 0;
        __syncthreads();
        sh[t] += v;
        __syncthreads();
    }
    int run = ((t == 0) ? 0 : sh[t - 1]) + base_blk;
#pragma unroll
    for (int i = 0; i < 4; i++) {
        int idx = base + i;
        if (idx < N) {
            rowptr[idx] = run;
            run += c[i];
        }
    }
    if (blockIdx.x == 0 && t == 0) rowptr[N] = total;
}

// ---------- K3: CSR scatter, no atomics, 4 B payload, 4 edges/thread ----------
__global__ void k_scatter(const void* __restrict__ edges,
                          const unsigned short* __restrict__ rank,
                          const int* __restrict__ rowptr,
                          int* __restrict__ csr_src, int E) {
    int e0 = (blockIdx.x * blockDim.x + threadIdx.x) * 4;
    if (e0 >= E) return;
    int s[4], d[4];
    if (e0 + 3 < E) {
        if (sniff_is64(edges)) {
            const long long* p = (const long long*)edges;
            int4 a0 = *(const int4*)&p[e0];
            int4 a1 = *(const int4*)&p[e0 + 2];
            int4 b0 = *(const int4*)&p[(size_t)E + e0];
            int4 b1 = *(const int4*)&p[(size_t)E + e0 + 2];
            s[0] = a0.x; s[1] = a0.z; s[2] = a1.x; s[3] = a1.z;
            d[0] = b0.x; d[1] = b0.z; d[2] = b1.x; d[3] = b1.z;
        } else {
            const int* p = (const int*)edges;
            int4 a = *(const int4*)&p[e0];
            int4 b = *(const int4*)&p[E + e0];
            s[0] = a.x; s[1] = a.y; s[2] = a.z; s[3] = a.w;
            d[0] = b.x; d[1] = b.y; d[2] = b.z; d[3] = b.w;
        }
        ushort4 r = *(const ushort4*)&rank[e0];
        csr_src[rowptr[d[0]] + r.x] = s[0];
        csr_src[rowptr[d[1]] + r.y] = s[1];
        csr_src[rowptr[d[2]] + r.z] = s[2];
        csr_src[rowptr[d[3]] + r.w] = s[3];
    } else {
        bool is64 = sniff_is64(edges);
        for (int i = 0; i < 4; i++) {
            if (e0 + i >= E) break;
            int sv, dv;
            if (is64) {
                const long long* p = (const long long*)edges;
                sv = (int)p[e0 + i];
                dv = (int)p[(size_t)E + e0 + i];
            } else {
                const int* p = (const int*)edges;
                sv = p[e0 + i];
                dv = p[E + e0 + i];
            }
            csr_src[rowptr[dv] + rank[e0 + i]] = sv;
        }
    }
}

// ---------- K4: per-node gather softmax-aggregate + bias + L2 normalize ----------
// 1 wave/node, 2 channels/lane (ushort2), half-waves cover 2 src rows per load,
// 8 gather loads in flight.
__global__ __launch_bounds__(256) void k_agg(const unsigned short* __restrict__ h16,
                                             const int* __restrict__ csr_src,
                                             const int* __restrict__ rowptr,
                                             const float* __restrict__ asrc,
                                             const float* __restrict__ adst,
                                             const float* __restrict__ bias,
                                             float* __restrict__ out, int N) {
    __shared__ float2 stage[4][64];   // wave-private
    int lane = threadIdx.x & 63;
    int wid = threadIdx.x >> 6;
    int node = blockIdx.x * 4 + wid;
    if (node >= N) return;
    int half = lane >> 5;
    int ch2 = (lane & 31) * 2;

    float aD = adst[node];
    // analytic self loop (h row counted in half 0 only)
    float a = aD + asrc[node];
    a = a > 0.f ? a : NEG_SLOPE * a;
    float w_self = __expf(a);
    unsigned hv = *(const unsigned*)&h16[(size_t)node * OUT_CH + ch2];
    float wse = half ? 0.f : w_self;
    float accx = wse * __uint_as_float(hv << 16);
    float accy = wse * __uint_as_float(hv & 0xFFFF0000u);
    float esum_lane = 0.f;

    int b0 = rowptr[node], b1 = rowptr[node + 1];
    for (int base = b0; base < b1; base += 64) {
        int idx = base + lane;
        int sv = 0;
        float wv = 0.f;
        if (idx < b1) {
            sv = csr_src[idx];                     // coalesced
            float av = aD + asrc[sv];              // parallel gather (L2-hot)
            av = av > 0.f ? av : NEG_SLOPE * av;
            wv = __expf(av);                       // once per edge
        }
        esum_lane += wv;
        stage[wid][lane] = make_float2(__int_as_float(sv), wv);

        int n = min(64, b1 - base);
        for (int j = 0; j < n; j += 16) {
#pragma unroll
            for (int k = 0; k < 8; k++) {
                float2 p = stage[wid][j + 2 * k + half];   // 2-addr broadcast, free
                int s = __float_as_int(p.x);
                unsigned v = *(const unsigned*)&h16[((size_t)s << 6) + ch2];
                accx = fmaf(p.y, __uint_as_float(v << 16), accx);
                accy = fmaf(p.y, __uint_as_float(v & 0xFFFF0000u), accy);
            }
        }
    }
    // combine half-waves (even rows in lanes 0-31, odd rows in 32-63)
    accx += __shfl_xor(accx, 32, 64);
    accy += __shfl_xor(accy, 32, 64);
#pragma unroll
    for (int m = 32; m >= 1; m >>= 1) esum_lane += __shfl_xor(esum_lane, m, 64);
    float esum = esum_lane + w_self;

    float inv = 1.f / (esum + 1e-16f);
    float2 bv = *(const float2*)&bias[ch2];
    float vx = accx * inv + bv.x;
    float vy = accy * inv + bv.y;
    float ss = vx * vx + vy * vy;
#pragma unroll
    for (int m = 16; m >= 1; m >>= 1) ss += __shfl_xor(ss, m, 64);   // within half
    float rinv = 1.f / fmaxf(sqrtf(ss), 1e-12f);
    if (!half)
        *(float2*)&out[(size_t)node * OUT_CH + ch2] = make_float2(vx * rinv, vy * rinv);
}

extern "C" void kernel_launch(void* const* d_in, const int* in_sizes, int n_in,
                              void* d_out, int out_size, void* d_ws, size_t ws_size,
                              hipStream_t stream) {
    const float* x    = (const float*)d_in[0];
    const void*  edges = d_in[1];
    const float* W    = (const float*)d_in[2];
    const float* att  = (const float*)d_in[3];
    const float* bias = (const float*)d_in[4];
    float* out = (float*)d_out;

    const int N = in_sizes[0] / IN_CH;
    const int E = in_sizes[1] / 2;
    const int NB = (N + 1023) / 1024;          // scan blocks (<=256 supported)
    const int MMB = (N + 63) / 64;             // mm blocks
    const int CNTB = (E + 1023) / 1024;        // count blocks (4 edges/thread)

    char* ws = (char*)d_ws;
    size_t off = 0;
    auto alloc = [&](size_t bytes) -> void* {
        void* p = ws + off;
        off += bytes;
        off = (off + 255) & ~(size_t)255;
        return p;
    };
    int*            counts   = (int*)alloc((size_t)N * 4);
    int*            rowptr   = (int*)alloc((size_t)(N + 1) * 4);
    unsigned short* rank     = (unsigned short*)alloc((size_t)E * 2);
    int*            partials = (int*)alloc((size_t)256 * 4);
    unsigned short* h16      = (unsigned short*)alloc((size_t)N * OUT_CH * 2);
    float*          asrc     = (float*)alloc((size_t)N * 4);
    float*          adst     = (float*)alloc((size_t)N * 4);
    int*            csr_src  = (int*)alloc((size_t)E * 4);

    hipMemsetAsync(counts, 0, (size_t)N * 4, stream);
    k_mm_count<<<MMB + CNTB, 256, 0, stream>>>(x, W, att, h16, asrc, adst, N,
                                               edges, counts, rank, E, MMB, CNTB);
    k_scanA<<<NB, 256, 0, stream>>>(counts, partials, N);
    k_scanC<<<NB, 256, 0, stream>>>(counts, partials, NB, E, rowptr, N);
    k_scatter<<<(E + 1023) / 1024, 256, 0, stream>>>(edges, rank, rowptr,
                                                     csr_src, E);
    k_agg<<<(N + 3) / 4, 256, 0, stream>>>(h16, csr_src, rowptr, asrc, adst,
                                           bias, out, N);
}

// Round 9
// 179.208 us; speedup vs baseline: 1.0035x; 1.0035x over previous
//
#include <hip/hip_runtime.h>
#include <math.h>

#define IN_CH 128
#define OUT_CH 64
#define NEG_SLOPE 0.2f

// ---------- bf16 helpers ----------
__device__ __forceinline__ unsigned short f2bf(float f) {
    unsigned u = __float_as_uint(f);
    unsigned r = (u + 0x7FFFu + ((u >> 16) & 1u)) >> 16;   // round-nearest-even
    return (unsigned short)r;
}

// ---------- edge dtype sniff: int64 little-endian => odd int32 words are 0 ----------
__device__ __forceinline__ bool sniff_is64(const void* edges) {
    const unsigned* up = (const unsigned*)edges;
    bool is64 = true;
#pragma unroll
    for (int k = 0; k < 16; k++) is64 = is64 && (up[2 * k + 1] == 0u);
    return is64;
}

// ---------- K1: degree count + rank, 4 edges/thread, NO LDS, standalone ----------
// Atomic-latency bound: needs max occupancy (VGPR~8, zero LDS -> 32 waves/CU).
__global__ void k_count(const void* __restrict__ edges, int* __restrict__ counts,
                        unsigned short* __restrict__ rank, int E) {
    int e0 = (blockIdx.x * blockDim.x + threadIdx.x) * 4;
    if (e0 >= E) return;
    int d[4];
    if (sniff_is64(edges)) {
        const long long* p = (const long long*)edges;
        if (e0 + 3 < E) {
            int4 v0 = *(const int4*)&p[(size_t)E + e0];       // 16B aligned
            int4 v1 = *(const int4*)&p[(size_t)E + e0 + 2];
            d[0] = v0.x; d[1] = v0.z; d[2] = v1.x; d[3] = v1.z;
        } else {
            for (int i = 0; i < 4; i++)
                d[i] = (e0 + i < E) ? (int)p[(size_t)E + e0 + i] : 0;
        }
    } else {
        const int* p = (const int*)edges;
        if (e0 + 3 < E) {
            int4 v = *(const int4*)&p[E + e0];
            d[0] = v.x; d[1] = v.y; d[2] = v.z; d[3] = v.w;
        } else {
            for (int i = 0; i < 4; i++)
                d[i] = (e0 + i < E) ? p[E + e0 + i] : 0;
        }
    }
    if (e0 + 3 < E) {
        ushort4 r;
        r.x = (unsigned short)atomicAdd(counts + d[0], 1);
        r.y = (unsigned short)atomicAdd(counts + d[1], 1);
        r.z = (unsigned short)atomicAdd(counts + d[2], 1);
        r.w = (unsigned short)atomicAdd(counts + d[3], 1);
        *(ushort4*)&rank[e0] = r;
    } else {
        for (int i = 0; i < 4; i++)
            if (e0 + i < E)
                rank[e0 + i] = (unsigned short)atomicAdd(counts + d[i], 1);
    }
}

// ---------- K2a: per-block sums of counts (1024 elems/block) ----------
__global__ __launch_bounds__(256) void k_scanA(const int* __restrict__ counts,
                                               int* __restrict__ partials, int N) {
    __shared__ int red[256];
    int t = threadIdx.x;
    int base = blockIdx.x * 1024 + t * 4;
    int s = 0;
    if (base + 3 < N) {
        int4 v = *(const int4*)(counts + base);
        s = v.x + v.y + v.z + v.w;
    } else {
        for (int i = 0; i < 4; i++) if (base + i < N) s += counts[base + i];
    }
    red[t] = s;
    __syncthreads();
    for (int off = 128; off > 0; off >>= 1) {
        if (t < off) red[t] += red[t + off];
        __syncthreads();
    }
    if (t == 0) partials[blockIdx.x] = red[0];
}

// ---------- K2b: each block scans the partials itself, then re-scans its chunk ----------
__global__ __launch_bounds__(256) void k_scanC(const int* __restrict__ counts,
                                               const int* __restrict__ partials,
                                               int nb, int total,
                                               int* __restrict__ rowptr, int N) {
    __shared__ int shp[256];
    __shared__ int sh[256];
    int t = threadIdx.x;
    shp[t] = (t < nb) ? partials[t] : 0;
    __syncthreads();
    for (int off = 1; off < 256; off <<= 1) {
        int v = (t >= off) ? shp[t - off] : 0;
        __syncthreads();
        shp[t] += v;
        __syncthreads();
    }
    int base_blk = (blockIdx.x == 0) ? 0 : shp[blockIdx.x - 1];

    int base = blockIdx.x * 1024 + t * 4;
    int c[4];
    int s = 0;
#pragma unroll
    for (int i = 0; i < 4; i++) {
        int idx = base + i;
        c[i] = (idx < N) ? counts[idx] : 0;
        s += c[i];
    }
    sh[t] = s;
    __syncthreads();
    for (int off = 1; off < 256; off <<= 1) {
        int v = (t >= off) ? sh[t - off] : 0;
        __syncthreads();
        sh[t] += v;
        __syncthreads();
    }
    int run = ((t == 0) ? 0 : sh[t - 1]) + base_blk;
#pragma unroll
    for (int i = 0; i < 4; i++) {
        int idx = base + i;
        if (idx < N) {
            rowptr[idx] = run;
            run += c[i];
        }
    }
    if (blockIdx.x == 0 && t == 0) rowptr[N] = total;
}

// ---------- K3 (fused, interleaved): even blocks mm, odd blocks scatter ----------
// mm (782 blocks): h16 = bf16(x@W) + att dots, W staged in 32KB LDS, VALU-bound.
// scatter (782 blocks): CSR scatter, 4 edges/thread — fire-and-forget stores +
// latency-tolerant rowptr gathers, hides fully under the mm blocks.
__global__ __launch_bounds__(256) void k_mm_scatter(
        const float* __restrict__ x, const float* __restrict__ W,
        const float* __restrict__ att, unsigned short* __restrict__ h16,
        float* __restrict__ asrc, float* __restrict__ adst, int N,
        const void* __restrict__ edges, const unsigned short* __restrict__ rank,
        const int* __restrict__ rowptr, int* __restrict__ csr_src,
        int E, int mmb, int scb) {
    __shared__ float Ws[IN_CH * OUT_CH];   // 32 KB (mm role only)
    int t = threadIdx.x;
    int bid = blockIdx.x;
    int lo = min(mmb, scb), M2 = 2 * lo;
    int role, id;   // role 0 = mm, 1 = scatter
    if (bid < M2) { role = bid & 1; id = bid >> 1; }
    else          { role = (mmb > scb) ? 0 : 1; id = bid - M2 + lo; }

    if (role == 1) {
        // ----- scatter path: 4 edges/thread -----
        int e0 = (id * 256 + t) * 4;
        if (e0 >= E) return;
        int s[4], d[4];
        if (e0 + 3 < E) {
            if (sniff_is64(edges)) {
                const long long* p = (const long long*)edges;
                int4 a0 = *(const int4*)&p[e0];
                int4 a1 = *(const int4*)&p[e0 + 2];
                int4 b0 = *(const int4*)&p[(size_t)E + e0];
                int4 b1 = *(const int4*)&p[(size_t)E + e0 + 2];
                s[0] = a0.x; s[1] = a0.z; s[2] = a1.x; s[3] = a1.z;
                d[0] = b0.x; d[1] = b0.z; d[2] = b1.x; d[3] = b1.z;
            } else {
                const int* p = (const int*)edges;
                int4 a = *(const int4*)&p[e0];
                int4 b = *(const int4*)&p[E + e0];
                s[0] = a.x; s[1] = a.y; s[2] = a.z; s[3] = a.w;
                d[0] = b.x; d[1] = b.y; d[2] = b.z; d[3] = b.w;
            }
            ushort4 r = *(const ushort4*)&rank[e0];
            csr_src[rowptr[d[0]] + r.x] = s[0];
            csr_src[rowptr[d[1]] + r.y] = s[1];
            csr_src[rowptr[d[2]] + r.z] = s[2];
            csr_src[rowptr[d[3]] + r.w] = s[3];
        } else {
            bool is64 = sniff_is64(edges);
            for (int i = 0; i < 4; i++) {
                if (e0 + i >= E) break;
                int sv, dv;
                if (is64) {
                    const long long* p = (const long long*)edges;
                    sv = (int)p[e0 + i];
                    dv = (int)p[(size_t)E + e0 + i];
                } else {
                    const int* p = (const int*)edges;
                    sv = p[e0 + i];
                    dv = p[E + e0 + i];
                }
                csr_src[rowptr[dv] + rank[e0 + i]] = sv;
            }
        }
        return;
    }

    // ----- mm path -----
    for (int i = t * 4; i < IN_CH * OUT_CH; i += 256 * 4)
        *(float4*)&Ws[i] = *(const float4*)&W[i];
    int cg = t & 15, g = t >> 4;
    float4 att_d = *(const float4*)&att[cg * 4];        // dst half: att[0:64]
    float4 att_s = *(const float4*)&att[64 + cg * 4];   // src half: att[64:128]
    __syncthreads();

    int n0 = id * 64 + g * 4;
    int nn[4];
#pragma unroll
    for (int m = 0; m < 4; m++) nn[m] = min(n0 + m, N - 1);

    float4 acc[4];
#pragma unroll
    for (int m = 0; m < 4; m++) acc[m] = make_float4(0.f, 0.f, 0.f, 0.f);

#pragma unroll 2
    for (int k4 = 0; k4 < IN_CH / 4; k4++) {
        float4 xv[4];
#pragma unroll
        for (int m = 0; m < 4; m++)
            xv[m] = *(const float4*)&x[(size_t)nn[m] * IN_CH + k4 * 4];
        float4 wv[4];
#pragma unroll
        for (int j = 0; j < 4; j++)
            wv[j] = *(const float4*)&Ws[(k4 * 4 + j) * OUT_CH + cg * 4];
#pragma unroll
        for (int m = 0; m < 4; m++) {
            acc[m].x = fmaf(xv[m].x, wv[0].x, acc[m].x);
            acc[m].y = fmaf(xv[m].x, wv[0].y, acc[m].y);
            acc[m].z = fmaf(xv[m].x, wv[0].z, acc[m].z);
            acc[m].w = fmaf(xv[m].x, wv[0].w, acc[m].w);
            acc[m].x = fmaf(xv[m].y, wv[1].x, acc[m].x);
            acc[m].y = fmaf(xv[m].y, wv[1].y, acc[m].y);
            acc[m].z = fmaf(xv[m].y, wv[1].z, acc[m].z);
            acc[m].w = fmaf(xv[m].y, wv[1].w, acc[m].w);
            acc[m].x = fmaf(xv[m].z, wv[2].x, acc[m].x);
            acc[m].y = fmaf(xv[m].z, wv[2].y, acc[m].y);
            acc[m].z = fmaf(xv[m].z, wv[2].z, acc[m].z);
            acc[m].w = fmaf(xv[m].z, wv[2].w, acc[m].w);
            acc[m].x = fmaf(xv[m].w, wv[3].x, acc[m].x);
            acc[m].y = fmaf(xv[m].w, wv[3].y, acc[m].y);
            acc[m].z = fmaf(xv[m].w, wv[3].z, acc[m].z);
            acc[m].w = fmaf(xv[m].w, wv[3].w, acc[m].w);
        }
    }

#pragma unroll
    for (int m = 0; m < 4; m++) {
        int node = n0 + m;
        if (node < N) {
            ushort4 hv;
            hv.x = f2bf(acc[m].x);
            hv.y = f2bf(acc[m].y);
            hv.z = f2bf(acc[m].z);
            hv.w = f2bf(acc[m].w);
            *(ushort4*)&h16[(size_t)node * OUT_CH + cg * 4] = hv;
        }
        float pd = acc[m].x * att_d.x + acc[m].y * att_d.y +
                   acc[m].z * att_d.z + acc[m].w * att_d.w;
        float ps = acc[m].x * att_s.x + acc[m].y * att_s.y +
                   acc[m].z * att_s.z + acc[m].w * att_s.w;
#pragma unroll
        for (int msk = 1; msk < 16; msk <<= 1) {
            pd += __shfl_xor(pd, msk, 64);
            ps += __shfl_xor(ps, msk, 64);
        }
        if (cg == 0 && node < N) { adst[node] = pd; asrc[node] = ps; }
    }
}

// ---------- K4: per-node gather softmax-aggregate + bias + L2 normalize ----------
// 1 wave/node, 2 channels/lane (ushort2), half-waves cover 2 src rows per load,
// 8 gather loads in flight.
__global__ __launch_bounds__(256) void k_agg(const unsigned short* __restrict__ h16,
                                             const int* __restrict__ csr_src,
                                             const int* __restrict__ rowptr,
                                             const float* __restrict__ asrc,
                                             const float* __restrict__ adst,
                                             const float* __restrict__ bias,
                                             float* __restrict__ out, int N) {
    __shared__ float2 stage[4][64];   // wave-private
    int lane = threadIdx.x & 63;
    int wid = threadIdx.x >> 6;
    int node = blockIdx.x * 4 + wid;
    if (node >= N) return;
    int half = lane >> 5;
    int ch2 = (lane & 31) * 2;

    float aD = adst[node];
    // analytic self loop (h row counted in half 0 only)
    float a = aD + asrc[node];
    a = a > 0.f ? a : NEG_SLOPE * a;
    float w_self = __expf(a);
    unsigned hv = *(const unsigned*)&h16[(size_t)node * OUT_CH + ch2];
    float wse = half ? 0.f : w_self;
    float accx = wse * __uint_as_float(hv << 16);
    float accy = wse * __uint_as_float(hv & 0xFFFF0000u);
    float esum_lane = 0.f;

    int b0 = rowptr[node], b1 = rowptr[node + 1];
    for (int base = b0; base < b1; base += 64) {
        int idx = base + lane;
        int sv = 0;
        float wv = 0.f;
        if (idx < b1) {
            sv = csr_src[idx];                     // coalesced
            float av = aD + asrc[sv];              // parallel gather (L2-hot)
            av = av > 0.f ? av : NEG_SLOPE * av;
            wv = __expf(av);                       // once per edge
        }
        esum_lane += wv;
        stage[wid][lane] = make_float2(__int_as_float(sv), wv);

        int n = min(64, b1 - base);
        for (int j = 0; j < n; j += 16) {
#pragma unroll
            for (int k = 0; k < 8; k++) {
                float2 p = stage[wid][j + 2 * k + half];   // 2-addr broadcast, free
                int s = __float_as_int(p.x);
                unsigned v = *(const unsigned*)&h16[((size_t)s << 6) + ch2];
                accx = fmaf(p.y, __uint_as_float(v << 16), accx);
                accy = fmaf(p.y, __uint_as_float(v & 0xFFFF0000u), accy);
            }
        }
    }
    // combine half-waves (even rows in lanes 0-31, odd rows in 32-63)
    accx += __shfl_xor(accx, 32, 64);
    accy += __shfl_xor(accy, 32, 64);
#pragma unroll
    for (int m = 32; m >= 1; m >>= 1) esum_lane += __shfl_xor(esum_lane, m, 64);
    float esum = esum_lane + w_self;

    float inv = 1.f / (esum + 1e-16f);
    float2 bv = *(const float2*)&bias[ch2];
    float vx = accx * inv + bv.x;
    float vy = accy * inv + bv.y;
    float ss = vx * vx + vy * vy;
#pragma unroll
    for (int m = 16; m >= 1; m >>= 1) ss += __shfl_xor(ss, m, 64);   // within half
    float rinv = 1.f / fmaxf(sqrtf(ss), 1e-12f);
    if (!half)
        *(float2*)&out[(size_t)node * OUT_CH + ch2] = make_float2(vx * rinv, vy * rinv);
}

extern "C" void kernel_launch(void* const* d_in, const int* in_sizes, int n_in,
                              void* d_out, int out_size, void* d_ws, size_t ws_size,
                              hipStream_t stream) {
    const float* x    = (const float*)d_in[0];
    const void*  edges = d_in[1];
    const float* W    = (const float*)d_in[2];
    const float* att  = (const float*)d_in[3];
    const float* bias = (const float*)d_in[4];
    float* out = (float*)d_out;

    const int N = in_sizes[0] / IN_CH;
    const int E = in_sizes[1] / 2;
    const int NB = (N + 1023) / 1024;          // scan blocks (<=256 supported)
    const int MMB = (N + 63) / 64;             // mm blocks
    const int SCB = (E + 1023) / 1024;         // scatter blocks (4 edges/thread)

    char* ws = (char*)d_ws;
    size_t off = 0;
    auto alloc = [&](size_t bytes) -> void* {
        void* p = ws + off;
        off += bytes;
        off = (off + 255) & ~(size_t)255;
        return p;
    };
    int*            counts   = (int*)alloc((size_t)N * 4);
    int*            rowptr   = (int*)alloc((size_t)(N + 1) * 4);
    unsigned short* rank     = (unsigned short*)alloc((size_t)E * 2);
    int*            partials = (int*)alloc((size_t)256 * 4);
    unsigned short* h16      = (unsigned short*)alloc((size_t)N * OUT_CH * 2);
    float*          asrc     = (float*)alloc((size_t)N * 4);
    float*          adst     = (float*)alloc((size_t)N * 4);
    int*            csr_src  = (int*)alloc((size_t)E * 4);

    hipMemsetAsync(counts, 0, (size_t)N * 4, stream);
    k_count<<<(E + 1023) / 1024, 256, 0, stream>>>(edges, counts, rank, E);
    k_scanA<<<NB, 256, 0, stream>>>(counts, partials, N);
    k_scanC<<<NB, 256, 0, stream>>>(counts, partials, NB, E, rowptr, N);
    k_mm_scatter<<<MMB + SCB, 256, 0, stream>>>(x, W, att, h16, asrc, adst, N,
                                                edges, rank, rowptr, csr_src,
                                                E, MMB, SCB);
    k_agg<<<(N + 3) / 4, 256, 0, stream>>>(h16, csr_src, rowptr, asrc, adst,
                                           bias, out, N);
}

// Round 10
// 143.444 us; speedup vs baseline: 1.2537x; 1.2493x over previous
//
#include <hip/hip_runtime.h>
#include <math.h>

#define IN_CH 128
#define OUT_CH 64
#define NEG_SLOPE 0.2f
#define CAP 64   // slots per node; mean degree 16, P(deg>64) ~ 1e-16 for uniform dst

// ---------- bf16 helpers ----------
__device__ __forceinline__ unsigned short f2bf(float f) {
    unsigned u = __float_as_uint(f);
    unsigned r = (u + 0x7FFFu + ((u >> 16) & 1u)) >> 16;   // round-nearest-even
    return (unsigned short)r;
}

// ---------- edge dtype sniff: int64 little-endian => odd int32 words are 0 ----------
__device__ __forceinline__ bool sniff_is64(const void* edges) {
    const unsigned* up = (const unsigned*)edges;
    bool is64 = true;
#pragma unroll
    for (int k = 0; k < 16; k++) is64 = is64 && (up[2 * k + 1] == 0u);
    return is64;
}

// ---------- K1 (fused, interleaved): even blocks mm, odd blocks count+scatter ----------
// mm (782 blocks): h16 = bf16(x@W) + att dots, W staged in 32KB LDS, VALU-bound.
// cs (782 blocks): one pass over edges: rank = atomicAdd(counts+d), slots[d*64+rank]=s.
// No scan, no rank array, no second edge pass. Overflow (deg>CAP) -> list, consumed
// by k_agg's cold path (never triggers for this distribution, correct if it does).
__global__ __launch_bounds__(256) void k_mm_cs(
        const float* __restrict__ x, const float* __restrict__ W,
        const float* __restrict__ att, unsigned short* __restrict__ h16,
        float* __restrict__ asrc, float* __restrict__ adst, int N,
        const void* __restrict__ edges, int* __restrict__ counts,
        int* __restrict__ slots, int* __restrict__ oflow_cnt,
        int2* __restrict__ oflow, int E, int mmb, int csb) {
    __shared__ float Ws[IN_CH * OUT_CH];   // 32 KB (mm role only)
    int t = threadIdx.x;
    int bid = blockIdx.x;
    int lo = min(mmb, csb), M2 = 2 * lo;
    int role, id;   // role 0 = mm, 1 = count+scatter
    if (bid < M2) { role = bid & 1; id = bid >> 1; }
    else          { role = (mmb > csb) ? 0 : 1; id = bid - M2 + lo; }

    if (role == 1) {
        // ----- count+scatter path: 4 edges/thread, single edge pass -----
        int e0 = (id * 256 + t) * 4;
        if (e0 >= E) return;
        int s[4], d[4];
        bool full = (e0 + 3 < E);
        if (full) {
            if (sniff_is64(edges)) {
                const long long* p = (const long long*)edges;
                int4 a0 = *(const int4*)&p[e0];
                int4 a1 = *(const int4*)&p[e0 + 2];
                int4 b0 = *(const int4*)&p[(size_t)E + e0];
                int4 b1 = *(const int4*)&p[(size_t)E + e0 + 2];
                s[0] = a0.x; s[1] = a0.z; s[2] = a1.x; s[3] = a1.z;
                d[0] = b0.x; d[1] = b0.z; d[2] = b1.x; d[3] = b1.z;
            } else {
                const int* p = (const int*)edges;
                int4 a = *(const int4*)&p[e0];
                int4 b = *(const int4*)&p[E + e0];
                s[0] = a.x; s[1] = a.y; s[2] = a.z; s[3] = a.w;
                d[0] = b.x; d[1] = b.y; d[2] = b.z; d[3] = b.w;
            }
#pragma unroll
            for (int i = 0; i < 4; i++) {
                int r = atomicAdd(counts + d[i], 1);
                if (r < CAP) {
                    slots[((size_t)d[i] << 6) + r] = s[i];
                } else {
                    int p = atomicAdd(oflow_cnt, 1);
                    oflow[p] = make_int2(s[i], d[i]);
                }
            }
        } else {
            bool is64 = sniff_is64(edges);
            for (int i = 0; i < 4; i++) {
                if (e0 + i >= E) break;
                int sv, dv;
                if (is64) {
                    const long long* p = (const long long*)edges;
                    sv = (int)p[e0 + i];
                    dv = (int)p[(size_t)E + e0 + i];
                } else {
                    const int* p = (const int*)edges;
                    sv = p[e0 + i];
                    dv = p[E + e0 + i];
                }
                int r = atomicAdd(counts + dv, 1);
                if (r < CAP) {
                    slots[((size_t)dv << 6) + r] = sv;
                } else {
                    int p2 = atomicAdd(oflow_cnt, 1);
                    oflow[p2] = make_int2(sv, dv);
                }
            }
        }
        return;
    }

    // ----- mm path -----
    for (int i = t * 4; i < IN_CH * OUT_CH; i += 256 * 4)
        *(float4*)&Ws[i] = *(const float4*)&W[i];
    int cg = t & 15, g = t >> 4;
    float4 att_d = *(const float4*)&att[cg * 4];        // dst half: att[0:64]
    float4 att_s = *(const float4*)&att[64 + cg * 4];   // src half: att[64:128]
    __syncthreads();

    int n0 = id * 64 + g * 4;
    int nn[4];
#pragma unroll
    for (int m = 0; m < 4; m++) nn[m] = min(n0 + m, N - 1);

    float4 acc[4];
#pragma unroll
    for (int m = 0; m < 4; m++) acc[m] = make_float4(0.f, 0.f, 0.f, 0.f);

#pragma unroll 2
    for (int k4 = 0; k4 < IN_CH / 4; k4++) {
        float4 xv[4];
#pragma unroll
        for (int m = 0; m < 4; m++)
            xv[m] = *(const float4*)&x[(size_t)nn[m] * IN_CH + k4 * 4];
        float4 wv[4];
#pragma unroll
        for (int j = 0; j < 4; j++)
            wv[j] = *(const float4*)&Ws[(k4 * 4 + j) * OUT_CH + cg * 4];
#pragma unroll
        for (int m = 0; m < 4; m++) {
            acc[m].x = fmaf(xv[m].x, wv[0].x, acc[m].x);
            acc[m].y = fmaf(xv[m].x, wv[0].y, acc[m].y);
            acc[m].z = fmaf(xv[m].x, wv[0].z, acc[m].z);
            acc[m].w = fmaf(xv[m].x, wv[0].w, acc[m].w);
            acc[m].x = fmaf(xv[m].y, wv[1].x, acc[m].x);
            acc[m].y = fmaf(xv[m].y, wv[1].y, acc[m].y);
            acc[m].z = fmaf(xv[m].y, wv[1].z, acc[m].z);
            acc[m].w = fmaf(xv[m].y, wv[1].w, acc[m].w);
            acc[m].x = fmaf(xv[m].z, wv[2].x, acc[m].x);
            acc[m].y = fmaf(xv[m].z, wv[2].y, acc[m].y);
            acc[m].z = fmaf(xv[m].z, wv[2].z, acc[m].z);
            acc[m].w = fmaf(xv[m].z, wv[2].w, acc[m].w);
            acc[m].x = fmaf(xv[m].w, wv[3].x, acc[m].x);
            acc[m].y = fmaf(xv[m].w, wv[3].y, acc[m].y);
            acc[m].z = fmaf(xv[m].w, wv[3].z, acc[m].z);
            acc[m].w = fmaf(xv[m].w, wv[3].w, acc[m].w);
        }
    }

#pragma unroll
    for (int m = 0; m < 4; m++) {
        int node = n0 + m;
        if (node < N) {
            ushort4 hv;
            hv.x = f2bf(acc[m].x);
            hv.y = f2bf(acc[m].y);
            hv.z = f2bf(acc[m].z);
            hv.w = f2bf(acc[m].w);
            *(ushort4*)&h16[(size_t)node * OUT_CH + cg * 4] = hv;
        }
        float pd = acc[m].x * att_d.x + acc[m].y * att_d.y +
                   acc[m].z * att_d.z + acc[m].w * att_d.w;
        float ps = acc[m].x * att_s.x + acc[m].y * att_s.y +
                   acc[m].z * att_s.z + acc[m].w * att_s.w;
#pragma unroll
        for (int msk = 1; msk < 16; msk <<= 1) {
            pd += __shfl_xor(pd, msk, 64);
            ps += __shfl_xor(ps, msk, 64);
        }
        if (cg == 0 && node < N) { adst[node] = pd; asrc[node] = ps; }
    }
}

// ---------- K2: per-node slot-gather softmax-aggregate + bias + L2 normalize ----------
// 1 wave/node, 2 channels/lane (ushort2), half-waves cover 2 src rows per load.
// Single 64-wide chunk (CAP=64). Overflow list consumed in a cold tail (oc==0 normally).
__global__ __launch_bounds__(256) void k_agg(const unsigned short* __restrict__ h16,
                                             const int* __restrict__ slots,
                                             const int* __restrict__ counts,
                                             const int* __restrict__ oflow_cnt,
                                             const int2* __restrict__ oflow,
                                             const float* __restrict__ asrc,
                                             const float* __restrict__ adst,
                                             const float* __restrict__ bias,
                                             float* __restrict__ out, int N) {
    __shared__ float2 stage[4][64];   // wave-private
    int lane = threadIdx.x & 63;
    int wid = threadIdx.x >> 6;
    int node = blockIdx.x * 4 + wid;
    if (node >= N) return;
    int half = lane >> 5;
    int ch2 = (lane & 31) * 2;

    float aD = adst[node];
    // analytic self loop (h row counted in half 0 only)
    float a = aD + asrc[node];
    a = a > 0.f ? a : NEG_SLOPE * a;
    float w_self = __expf(a);
    unsigned hv = *(const unsigned*)&h16[(size_t)node * OUT_CH + ch2];
    float wse = half ? 0.f : w_self;
    float accx = wse * __uint_as_float(hv << 16);
    float accy = wse * __uint_as_float(hv & 0xFFFF0000u);
    float esum_lane = 0.f;

    int c = counts[node];           // true degree (may exceed CAP; slots hold min)
    int cs = min(c, CAP);
    int sv = 0;
    float wv = 0.f;
    if (lane < cs) {
        sv = slots[((size_t)node << 6) + lane];   // coalesced 256B
        float av = aD + asrc[sv];                 // parallel gather (L2-hot)
        av = av > 0.f ? av : NEG_SLOPE * av;
        wv = __expf(av);                          // once per edge
    }
    esum_lane = wv;
    stage[wid][lane] = make_float2(__int_as_float(sv), wv);

    for (int j = 0; j < cs; j += 16) {
#pragma unroll
        for (int k = 0; k < 8; k++) {
            float2 p = stage[wid][j + 2 * k + half];   // 2-addr broadcast, free
            int s = __float_as_int(p.x);
            unsigned v = *(const unsigned*)&h16[((size_t)s << 6) + ch2];
            accx = fmaf(p.y, __uint_as_float(v << 16), accx);
            accy = fmaf(p.y, __uint_as_float(v & 0xFFFF0000u), accy);
        }
    }
    // combine half-waves (even rows in lanes 0-31, odd rows in 32-63)
    accx += __shfl_xor(accx, 32, 64);
    accy += __shfl_xor(accy, 32, 64);
#pragma unroll
    for (int m = 32; m >= 1; m >>= 1) esum_lane += __shfl_xor(esum_lane, m, 64);
    float esum = esum_lane + w_self;

    // cold overflow path (oc == 0 for this input; correct if not)
    int oc = *oflow_cnt;
    if (oc > 0) {
        for (int i = 0; i < oc; i++) {
            int2 e = oflow[i];
            if (e.y == node) {
                float av = aD + asrc[e.x];
                av = av > 0.f ? av : NEG_SLOPE * av;
                float w = __expf(av);
                esum += w;
                unsigned v = *(const unsigned*)&h16[((size_t)e.x << 6) + ch2];
                accx = fmaf(w, __uint_as_float(v << 16), accx);
                accy = fmaf(w, __uint_as_float(v & 0xFFFF0000u), accy);
            }
        }
    }

    float inv = 1.f / (esum + 1e-16f);
    float2 bv = *(const float2*)&bias[ch2];
    float vx = accx * inv + bv.x;
    float vy = accy * inv + bv.y;
    float ss = vx * vx + vy * vy;
#pragma unroll
    for (int m = 16; m >= 1; m >>= 1) ss += __shfl_xor(ss, m, 64);   // within half
    float rinv = 1.f / fmaxf(sqrtf(ss), 1e-12f);
    if (!half)
        *(float2*)&out[(size_t)node * OUT_CH + ch2] = make_float2(vx * rinv, vy * rinv);
}

extern "C" void kernel_launch(void* const* d_in, const int* in_sizes, int n_in,
                              void* d_out, int out_size, void* d_ws, size_t ws_size,
                              hipStream_t stream) {
    const float* x    = (const float*)d_in[0];
    const void*  edges = d_in[1];
    const float* W    = (const float*)d_in[2];
    const float* att  = (const float*)d_in[3];
    const float* bias = (const float*)d_in[4];
    float* out = (float*)d_out;

    const int N = in_sizes[0] / IN_CH;
    const int E = in_sizes[1] / 2;
    const int MMB = (N + 63) / 64;             // mm blocks
    const int CSB = (E + 1023) / 1024;         // count+scatter blocks (4 edges/thread)

    char* ws = (char*)d_ws;
    size_t off = 0;
    auto alloc = [&](size_t bytes) -> void* {
        void* p = ws + off;
        off += bytes;
        off = (off + 255) & ~(size_t)255;
        return p;
    };
    int*            counts   = (int*)alloc((size_t)(N + 64) * 4);  // +oflow_cnt tail
    int*            slots    = (int*)alloc((size_t)N * CAP * 4);   // 12.8 MB
    int2*           oflow    = (int2*)alloc((size_t)E * 8);        // never used in practice
    unsigned short* h16      = (unsigned short*)alloc((size_t)N * OUT_CH * 2);
    float*          asrc     = (float*)alloc((size_t)N * 4);
    float*          adst     = (float*)alloc((size_t)N * 4);
    int*            oflow_cnt = counts + N;

    hipMemsetAsync(counts, 0, (size_t)(N + 64) * 4, stream);
    k_mm_cs<<<MMB + CSB, 256, 0, stream>>>(x, W, att, h16, asrc, adst, N,
                                           edges, counts, slots, oflow_cnt,
                                           oflow, E, MMB, CSB);
    k_agg<<<(N + 3) / 4, 256, 0, stream>>>(h16, slots, counts, oflow_cnt, oflow,
                                           asrc, adst, bias, out, N);
}